// Round 1
// baseline (313.884 us; speedup 1.0000x reference)
//
#include <hip/hip_runtime.h>
#include <math.h>

// Octonion product via Cayley-Dickson over quaternions (matches reference's
// _oct_structure exactly, so no hand-transcribed 8x8x8 table to get wrong).
__device__ __forceinline__ void qmul(float w1, float x1, float y1, float z1,
                                     float w2, float x2, float y2, float z2,
                                     float& w, float& x, float& y, float& z) {
    w = w1 * w2 - x1 * x2 - y1 * y2 - z1 * z2;
    x = w1 * x2 + x1 * w2 + y1 * z2 - z1 * y2;
    y = w1 * y2 - x1 * z2 + y1 * w2 + z1 * x2;
    z = w1 * z2 + x1 * y2 - y1 * x2 + z1 * w2;
}

#define ITEMS_PER_BLOCK 64
#define F4_PER_ITEM 14          // 56 floats = 224 B per item
#define BYTES_PER_ITEM 224

// One wave per block. Wave stages its 64 items (14 KiB contiguous) into LDS
// via global_load_lds width=16 (fully coalesced: lane i <- base + i*16), then
// each lane gathers its own item from LDS. 14336 B LDS -> ~11 blocks/CU.
__global__ __launch_bounds__(64) void oct_fano_kernel(
    const float* __restrict__ in,    // (B, 7, 8) fp32
    const float* __restrict__ logs,  // scalar log_sensitivity
    float* __restrict__ out,         // (B,) fp32
    int B) {
    __shared__ float4 tile[ITEMS_PER_BLOCK * F4_PER_ITEM];  // 14336 B, linear copy

    const int lane = threadIdx.x;  // 0..63, single wave
    const size_t base_item = (size_t)blockIdx.x * ITEMS_PER_BLOCK;
    const char* gsrc = (const char*)in + base_item * BYTES_PER_ITEM;

    if (base_item + ITEMS_PER_BLOCK <= (size_t)B) {
        // Full tile: 14 x 1KiB chunks. LDS dest is wave-uniform base;
        // HW adds lane*16. Global src carries the per-lane offset.
#pragma unroll
        for (int c = 0; c < F4_PER_ITEM; c++) {
            __builtin_amdgcn_global_load_lds(
                (const __attribute__((address_space(1))) void*)(gsrc + (size_t)c * 1024 + (size_t)lane * 16),
                (__attribute__((address_space(3))) void*)((char*)tile + c * 1024),
                16, 0, 0);
        }
    } else {
        // Tail block (B % 64 != 0): guarded per-thread copy, rare path.
        int items = B - (int)base_item;
        if (items < 0) items = 0;
        const float4* g4 = (const float4*)gsrc;
        for (int idx = lane; idx < items * F4_PER_ITEM; idx += 64)
            tile[idx] = g4[idx];
    }
    // Drain the direct-to-LDS loads before ds_read (barrier also drains, but
    // be explicit for the single-wave case).
    asm volatile("s_waitcnt vmcnt(0)" ::: "memory");
    __syncthreads();

    const int b = (int)base_item + lane;
    if (b < B) {
        float x[7][8];
        const float4* my = tile + lane * F4_PER_ITEM;
#pragma unroll
        for (int k = 0; k < F4_PER_ITEM; k++) {
            float4 v = my[k];
            int r = k >> 1;
            int c = (k & 1) * 4;
            x[r][c + 0] = v.x;
            x[r][c + 1] = v.y;
            x[r][c + 2] = v.z;
            x[r][c + 3] = v.w;
        }

        // Normalize each of the 7 rows (norm = max(||x||, 1e-12))
#pragma unroll
        for (int r = 0; r < 7; r++) {
            float s = 0.f;
#pragma unroll
            for (int c = 0; c < 8; c++) s += x[r][c] * x[r][c];
            float n = fmaxf(sqrtf(s), 1e-12f);
            float inv = 1.0f / n;
#pragma unroll
            for (int c = 0; c < 8; c++) x[r][c] *= inv;
        }

        // 7 Fano lines: (i, j, k) = (l, (l+1)%7, (l+3)%7)
        float total = 0.f;
#pragma unroll
        for (int l = 0; l < 7; l++) {
            const float* a = x[l];
            const float* bb = x[(l + 1) % 7];
            const float* ck = x[(l + 3) % 7];

            float p0, p1, p2, p3, p4, p5, p6, p7;
            float t0, t1, t2, t3;
            // c1 = qmul(a1, b1) - qmul(conj(b2), a2)
            qmul(a[0], a[1], a[2], a[3], bb[0], bb[1], bb[2], bb[3], p0, p1, p2, p3);
            qmul(bb[4], -bb[5], -bb[6], -bb[7], a[4], a[5], a[6], a[7], t0, t1, t2, t3);
            p0 -= t0; p1 -= t1; p2 -= t2; p3 -= t3;
            // c2 = qmul(b2, a1) + qmul(a2, conj(b1))
            qmul(bb[4], bb[5], bb[6], bb[7], a[0], a[1], a[2], a[3], p4, p5, p6, p7);
            qmul(a[4], a[5], a[6], a[7], bb[0], -bb[1], -bb[2], -bb[3], t0, t1, t2, t3);
            p4 += t0; p5 += t1; p6 += t2; p7 += t3;

            float d0 = p0 - ck[0], d1 = p1 - ck[1], d2 = p2 - ck[2], d3 = p3 - ck[3];
            float d4 = p4 - ck[4], d5 = p5 - ck[5], d6 = p6 - ck[6], d7 = p7 - ck[7];
            total += d0 * d0 + d1 * d1 + d2 * d2 + d3 * d3 +
                     d4 * d4 + d5 * d5 + d6 * d6 + d7 * d7;
        }

        float avg = total * (1.0f / 7.0f);
        float phi = -logf(avg + 1e-8f) * expf(logs[0]);
        phi = fminf(fmaxf(phi, 0.0f), 10.0f);
        out[b] = phi;
    }
}

extern "C" void kernel_launch(void* const* d_in, const int* in_sizes, int n_in,
                              void* d_out, int out_size, void* d_ws, size_t ws_size,
                              hipStream_t stream) {
    const float* states = (const float*)d_in[0];
    const float* logs = (const float*)d_in[1];
    float* out = (float*)d_out;
    int B = in_sizes[0] / 56;  // 7*8 floats per batch
    int blocks = (B + ITEMS_PER_BLOCK - 1) / ITEMS_PER_BLOCK;
    oct_fano_kernel<<<blocks, 64, 0, stream>>>(states, logs, out, B);
}